// Round 6
// baseline (413.908 us; speedup 1.0000x reference)
//
#include <hip/hip_runtime.h>
#include <stdint.h>

#define N_ROWS 200000
#define NIMG   500
#define DMETA  24
#define WIDTH  32
#define HID    64
#define DEPTH  20
#define MC     32

// 32x32 transposed-MFMA structure (R5) + block-cooperative LDS double-buffer
// for per-layer weight frags (16KB/layer, reg-staged issue-early/write-late,
// 1 barrier/layer) + all biases staged to LDS once. 256-thr blocks (4 waves),
// 40.4KB LDS -> 4 blocks/CU = 16 waves/CU.

// ws layout: identical to rounds 4/5.
#define WB      64000
#define LSTR2   16768
#define OFF_WI  (WB + DEPTH * LSTR2)   // 399360
#define OFF_WS  (OFF_WI + 4096)        // 403456
#define OFF_BIQ (OFF_WS + 4096)        // 407552
#define OFF_BSQ (OFF_BIQ + 128)        // 407680
#define OFF_WOQ (OFF_BSQ + 128)        // 407808, end 408064

typedef __attribute__((ext_vector_type(8))) short bf16x8;
typedef __attribute__((ext_vector_type(4))) float f32x4;
typedef __attribute__((ext_vector_type(16))) float f32x16;

#define MFMA32(a, b, acc) __builtin_amdgcn_mfma_f32_32x32x16_bf16((a), (b), (acc), 0, 0, 0)
#define SWP(x, y) asm("v_permlane32_swap_b32 %0, %1" : "+v"(x), "+v"(y))
#define WOFFi(h5, reg) ((((reg) & 3) + 8 * ((reg) >> 2)) + 4 * (h5))

__device__ __forceinline__ uint32_t rotl32(uint32_t x, int r) {
    return (x << r) | (x >> (32 - r));
}

// JAX partitionable threefry, key (0,42)
__device__ __forceinline__ uint32_t tf_bits(uint32_t j) {
    const uint32_t ks1 = 42u, ks2 = 0x1BD11BDAu ^ 42u;
    uint32_t x0 = 0u, x1 = j + ks1;
#define R4(a,b,c,d) \
    x0 += x1; x1 = rotl32(x1,(a)); x1 ^= x0; \
    x0 += x1; x1 = rotl32(x1,(b)); x1 ^= x0; \
    x0 += x1; x1 = rotl32(x1,(c)); x1 ^= x0; \
    x0 += x1; x1 = rotl32(x1,(d)); x1 ^= x0;
    R4(13,15,26,6)  x0 += ks1; x1 += ks2 + 1u;
    R4(17,29,16,24) x0 += ks2; x1 += 0u + 2u;
    R4(13,15,26,6)                x1 += ks1 + 3u;
    R4(17,29,16,24) x0 += ks1; x1 += ks2 + 4u;
    R4(13,15,26,6)  x0 += ks2; x1 += 0u + 5u;
#undef R4
    return x0 ^ x1;
}

__device__ __forceinline__ float bits_to_normal(uint32_t b) {
    float f = __uint_as_float((b >> 9) | 0x3f800000u) - 1.0f;
    const float lo = -0.99999994f;
    float u = fmaxf(lo, f * 2.0f + lo);
    return 1.41421356f * erfinvf(u);
}

// split (prep, scalar)
__device__ __forceinline__ void split1(float x, short& hi, short& lo) {
    uint32_t b = __float_as_uint(x);
    uint32_t a = b + 0x8000u;
    hi = (short)(a >> 16);
    float r = x - __uint_as_float(a & 0xFFFF0000u);
    lo = (short)(__float_as_uint(r) >> 16);
}

__device__ __forceinline__ void split8p(const float* x, bf16x8& hi, bf16x8& lo) {
    uint32_t hu[4], lu[4];
#pragma unroll
    for (int p = 0; p < 4; ++p) {
        float x0 = x[2 * p], x1 = x[2 * p + 1];
        uint32_t h;
        asm("v_cvt_pk_bf16_f32 %0, %1, %2" : "=v"(h) : "v"(x0), "v"(x1));
        float r0 = x0 - __uint_as_float(h << 16);
        float r1 = x1 - __uint_as_float(h & 0xFFFF0000u);
        uint32_t l;
        asm("v_cvt_pk_bf16_f32 %0, %1, %2" : "=v"(l) : "v"(r0), "v"(r1));
        hu[p] = h;
        lu[p] = l;
    }
    __builtin_memcpy(&hi, hu, 16);
    __builtin_memcpy(&lo, lu, 16);
}

// build stage-1 B-frags for one tile: split h -> hi/lo words + half-swap
__device__ __forceinline__ void mkbfrag(const float* h, bf16x8* Bh, bf16x8* Bl) {
    uint32_t Hh[8], Hl[8];
#pragma unroll
    for (int p = 0; p < 8; ++p) {
        float x0 = h[2 * p], x1 = h[2 * p + 1];
        uint32_t wd;
        asm("v_cvt_pk_bf16_f32 %0, %1, %2" : "=v"(wd) : "v"(x0), "v"(x1));
        float r0 = x0 - __uint_as_float(wd << 16);
        float r1 = x1 - __uint_as_float(wd & 0xFFFF0000u);
        uint32_t ld;
        asm("v_cvt_pk_bf16_f32 %0, %1, %2" : "=v"(ld) : "v"(r0), "v"(r1));
        Hh[p] = wd;
        Hl[p] = ld;
    }
    SWP(Hh[0], Hh[2]); SWP(Hh[1], Hh[3]); SWP(Hh[4], Hh[6]); SWP(Hh[5], Hh[7]);
    SWP(Hl[0], Hl[2]); SWP(Hl[1], Hl[3]); SWP(Hl[4], Hl[6]); SWP(Hl[5], Hl[7]);
    __builtin_memcpy(&Bh[0], &Hh[0], 16);
    __builtin_memcpy(&Bh[1], &Hh[4], 16);
    __builtin_memcpy(&Bl[0], &Hl[0], 16);
    __builtin_memcpy(&Bl[1], &Hl[4], 16);
}

// 20 residual blocks, 2 tiles/wave; weights read from LDS double buffer,
// next layer reg-staged (issue-early / ds_write-late), biases from LDS.
__device__ __forceinline__ void mlp20_x2(
    float* h0, float* h1, char* lfr0, const char* lbias,
    const char* __restrict__ wsb, int wv, int lane, int h5) {
    const uint32_t lf = (uint32_t)(lane * 16);
    const uint32_t sc = (uint32_t)(wv * 4096) + lf;   // this wave's staging chunk
    uint32_t boff = 0;
    int cur = 0;
#pragma unroll 1
    for (int l = 0; l < DEPTH; ++l) {
        // issue next-layer frag loads early (land during compute)
        f32x4 stg[4];
        if (l < DEPTH - 1) {
            const char* srcn = wsb + WB + (l + 1) * LSTR2;
#pragma unroll
            for (int i = 0; i < 4; ++i)
                stg[i] = *(const f32x4*)(srcn + sc + (uint32_t)(i * 1024));
        }
        const char* cb = lfr0 + cur * 16384;
        // ---- stage-1 B prep (both tiles)
        bf16x8 B0h[2], B0l[2], B1h[2], B1l[2];
        mkbfrag(h0, B0h, B0l);
        mkbfrag(h1, B1h, B1l);
        // ---- stage 1: two M-tiles, bias quads (LDS) as C-init
        uint32_t P0[16], P1[16];
#pragma unroll
        for (int tm = 0; tm < 2; ++tm) {
            f32x16 acc0, acc1;
            {
                const char* bq = lbias + boff + (uint32_t)(tm * 128 + h5 * 64);
#pragma unroll
                for (int r = 0; r < 4; ++r) {
                    f32x4 q = *(const f32x4*)(bq + 16 * r);
#pragma unroll
                    for (int i = 0; i < 4; ++i) {
                        acc0[4 * r + i] = q[i];
                        acc1[4 * r + i] = q[i];
                    }
                }
            }
            const char* fa = cb + (uint32_t)(tm * 4096) + lf;
            bf16x8 a0h = *(const bf16x8*)(fa);
            bf16x8 a0l = *(const bf16x8*)(fa + 1024);
            bf16x8 a1h = *(const bf16x8*)(fa + 2048);
            bf16x8 a1l = *(const bf16x8*)(fa + 3072);
            acc0 = MFMA32(a0h, B0h[0], acc0);
            acc1 = MFMA32(a0h, B1h[0], acc1);
            acc0 = MFMA32(a0h, B0l[0], acc0);
            acc1 = MFMA32(a0h, B1l[0], acc1);
            acc0 = MFMA32(a0l, B0h[0], acc0);
            acc1 = MFMA32(a0l, B1h[0], acc1);
            acc0 = MFMA32(a1h, B0h[1], acc0);
            acc1 = MFMA32(a1h, B1h[1], acc1);
            acc0 = MFMA32(a1h, B0l[1], acc0);
            acc1 = MFMA32(a1h, B1l[1], acc1);
            acc0 = MFMA32(a1l, B0h[1], acc0);
            acc1 = MFMA32(a1l, B1h[1], acc1);
#pragma unroll
            for (int p = 0; p < 8; ++p) {
                float f0 = fmaxf(acc0[2 * p], 0.0f);
                float f1 = fmaxf(acc0[2 * p + 1], 0.0f);
                uint32_t wd;
                asm("v_cvt_pk_bf16_f32 %0, %1, %2" : "=v"(wd) : "v"(f0), "v"(f1));
                P0[tm * 8 + p] = wd;
                float g0 = fmaxf(acc1[2 * p], 0.0f);
                float g1 = fmaxf(acc1[2 * p + 1], 0.0f);
                uint32_t we;
                asm("v_cvt_pk_bf16_f32 %0, %1, %2" : "=v"(we) : "v"(g0), "v"(g1));
                P1[tm * 8 + p] = we;
            }
        }
        SWP(P0[0], P0[2]);  SWP(P0[1], P0[3]);  SWP(P0[4], P0[6]);   SWP(P0[5], P0[7]);
        SWP(P0[8], P0[10]); SWP(P0[9], P0[11]); SWP(P0[12], P0[14]); SWP(P0[13], P0[15]);
        SWP(P1[0], P1[2]);  SWP(P1[1], P1[3]);  SWP(P1[4], P1[6]);   SWP(P1[5], P1[7]);
        SWP(P1[8], P1[10]); SWP(P1[9], P1[11]); SWP(P1[12], P1[14]); SWP(P1[13], P1[15]);
        // ---- stage 2: acc init = h + b2 (LDS quad)
        f32x16 acc20, acc21;
        {
            const char* bq = lbias + boff + 256u + (uint32_t)(h5 * 64);
#pragma unroll
            for (int r = 0; r < 4; ++r) {
                f32x4 q = *(const f32x4*)(bq + 16 * r);
#pragma unroll
                for (int i = 0; i < 4; ++i) {
                    acc20[4 * r + i] = h0[4 * r + i] + q[i];
                    acc21[4 * r + i] = h1[4 * r + i] + q[i];
                }
            }
        }
#pragma unroll
        for (int ks = 0; ks < 4; ++ks) {
            bf16x8 Bk0, Bk1;
            __builtin_memcpy(&Bk0, &P0[ks * 4], 16);
            __builtin_memcpy(&Bk1, &P1[ks * 4], 16);
            const char* fa = cb + 8192u + (uint32_t)(ks * 2048) + lf;
            bf16x8 ah = *(const bf16x8*)(fa);
            bf16x8 al = *(const bf16x8*)(fa + 1024);
            acc20 = MFMA32(ah, Bk0, acc20);
            acc21 = MFMA32(ah, Bk1, acc21);
            acc20 = MFMA32(al, Bk0, acc20);
            acc21 = MFMA32(al, Bk1, acc21);
        }
#pragma unroll
        for (int i = 0; i < 16; ++i) { h0[i] = acc20[i]; h1[i] = acc21[i]; }
        // write-late: staged frags -> other buffer, then barrier
        if (l < DEPTH - 1) {
            char* db = lfr0 + (cur ^ 1) * 16384;
#pragma unroll
            for (int i = 0; i < 4; ++i)
                *(f32x4*)(db + sc + (uint32_t)(i * 1024)) = stg[i];
        }
        __syncthreads();
        cur ^= 1;
        boff += 384;
    }
}

// transposed input projection for both tiles (weight frags from global ws)
__device__ __forceinline__ void input_proj32_x2(
    const bf16x8* X0, const bf16x8* X1,
    const char* __restrict__ wsb, uint32_t wfoff, uint32_t bqoff,
    float* h0, float* h1, int lane, int h5) {
    f32x16 acc0, acc1;
    {
        const char* bq = wsb + bqoff + (uint32_t)(h5 * 64);
#pragma unroll
        for (int r = 0; r < 4; ++r) {
            f32x4 q = *(const f32x4*)(bq + 16 * r);
#pragma unroll
            for (int i = 0; i < 4; ++i) { acc0[4 * r + i] = q[i]; acc1[4 * r + i] = q[i]; }
        }
    }
    const char* fa = wsb + wfoff + (uint32_t)(lane * 16);
    bf16x8 a0h = *(const bf16x8*)(fa);
    bf16x8 a0l = *(const bf16x8*)(fa + 1024);
    bf16x8 a1h = *(const bf16x8*)(fa + 2048);
    bf16x8 a1l = *(const bf16x8*)(fa + 3072);
    acc0 = MFMA32(a0h, X0[0], acc0);
    acc1 = MFMA32(a0h, X1[0], acc1);
    acc0 = MFMA32(a0h, X0[1], acc0);
    acc1 = MFMA32(a0h, X1[1], acc1);
    acc0 = MFMA32(a0l, X0[0], acc0);
    acc1 = MFMA32(a0l, X1[0], acc1);
    acc0 = MFMA32(a1h, X0[2], acc0);
    acc1 = MFMA32(a1h, X1[2], acc1);
    acc0 = MFMA32(a1h, X0[3], acc0);
    acc1 = MFMA32(a1h, X1[3], acc1);
    acc0 = MFMA32(a1l, X0[2], acc0);
    acc1 = MFMA32(a1l, X1[2], acc1);
#pragma unroll
    for (int i = 0; i < 16; ++i) { h0[i] = acc0[i]; h1[i] = acc1[i]; }
}

__device__ __forceinline__ void load_xfrags(
    const float* __restrict__ md, const float* __restrict__ iobs,
    const float* __restrict__ sig, int row, int h5, bf16x8* X) {
    float xa0[8], xa1[8];
    {
        const f32x4* rp = (const f32x4*)(md + (size_t)row * DMETA + 8 * h5);
        f32x4 a = rp[0], b = rp[1];
#pragma unroll
        for (int j = 0; j < 4; ++j) { xa0[j] = a[j]; xa0[4 + j] = b[j]; }
    }
    if (h5 == 0) {
        const f32x4* rp = (const f32x4*)(md + (size_t)row * DMETA + 16);
        f32x4 a = rp[0], b = rp[1];
#pragma unroll
        for (int j = 0; j < 4; ++j) { xa1[j] = a[j]; xa1[4 + j] = b[j]; }
    } else {
        xa1[0] = iobs ? iobs[row] : 0.0f;
        xa1[1] = sig ? sig[row] : 0.0f;
#pragma unroll
        for (int j = 2; j < 8; ++j) xa1[j] = 0.0f;
    }
    split8p(xa0, X[0], X[1]);
    split8p(xa1, X[2], X[3]);
}

// prep: unchanged ws builder (same layout as rounds 4/5)
__global__ __launch_bounds__(256) void prep_kernel(
    const float* __restrict__ w1, const float* __restrict__ w2,
    const float* __restrict__ wimg, const float* __restrict__ wsc,
    const float* __restrict__ b1, const float* __restrict__ b2,
    const float* __restrict__ bimg, const float* __restrict__ bsc,
    const float* __restrict__ wout, char* __restrict__ wsb) {
    int t = blockIdx.x * 256 + threadIdx.x;
    float* sums = (float*)wsb;
    if (t < 16000) { sums[t] = 0.0f; return; }
    t -= 16000;
    if (t < 40960) {  // W1^T frags: A[u][k] = W1[k][u]
        int l = t >> 11, r = t & 2047;
        int tm = r >> 10, ks = (r >> 9) & 1, lane = (r >> 3) & 63, j = r & 7;
        int k = 16 * ks + 8 * (lane >> 5) + j;
        int u = 32 * tm + (lane & 31);
        short hh, ll;
        split1(w1[l * 2048 + k * 64 + u], hh, ll);
        char* base = wsb + WB + l * LSTR2 + (tm * 2 + ks) * 2048 + 2 * (lane * 8 + j);
        *(short*)base = hh;
        *(short*)(base + 1024) = ll;
        return;
    }
    t -= 40960;
    if (t < 40960) {  // W2^T frags: A[w][u] = W2[u][w]
        int l = t >> 11, r = t & 2047;
        int ks = r >> 9, lane = (r >> 3) & 63, j = r & 7;
        int u = 16 * ks + 8 * (lane >> 5) + j;
        int w = lane & 31;
        short hh, ll;
        split1(w2[l * 2048 + u * 32 + w], hh, ll);
        char* base = wsb + WB + l * LSTR2 + 8192 + ks * 2048 + 2 * (lane * 8 + j);
        *(short*)base = hh;
        *(short*)(base + 1024) = ll;
        return;
    }
    t -= 40960;
    if (t < 1280) {  // b1 quads [l][tm][h5][reg]
        int l = t >> 6, r = t & 63;
        int tm = r >> 5, h5 = (r >> 4) & 1, reg = r & 15;
        *(float*)(wsb + WB + l * LSTR2 + 16384 + tm * 128 + h5 * 64 + reg * 4) =
            b1[l * 64 + 32 * tm + WOFFi(h5, reg)];
        return;
    }
    t -= 1280;
    if (t < 640) {  // b2 quads [l][h5][reg]
        int l = t >> 5, r = t & 31;
        int h5 = r >> 4, reg = r & 15;
        *(float*)(wsb + WB + l * LSTR2 + 16640 + h5 * 64 + reg * 4) =
            b2[l * 32 + WOFFi(h5, reg)];
        return;
    }
    t -= 640;
    if (t < 1024) {  // wimg^T frags (d padded 26->32)
        int ks = t >> 9, lane = (t >> 3) & 63, j = t & 7;
        int d = 16 * ks + 8 * (lane >> 5) + j, w = lane & 31;
        float v = (d < 26) ? wimg[d * 32 + w] : 0.0f;
        short hh, ll;
        split1(v, hh, ll);
        char* base = wsb + OFF_WI + ks * 2048 + 2 * (lane * 8 + j);
        *(short*)base = hh;
        *(short*)(base + 1024) = ll;
        return;
    }
    t -= 1024;
    if (t < 1024) {  // wsc^T frags (d padded 24->32)
        int ks = t >> 9, lane = (t >> 3) & 63, j = t & 7;
        int d = 16 * ks + 8 * (lane >> 5) + j, w = lane & 31;
        float v = (d < 24) ? wsc[d * 32 + w] : 0.0f;
        short hh, ll;
        split1(v, hh, ll);
        char* base = wsb + OFF_WS + ks * 2048 + 2 * (lane * 8 + j);
        *(short*)base = hh;
        *(short*)(base + 1024) = ll;
        return;
    }
    t -= 1024;
    if (t < 32) {
        int h5 = t >> 4, reg = t & 15;
        *(float*)(wsb + OFF_BIQ + h5 * 64 + reg * 4) = bimg[WOFFi(h5, reg)];
        return;
    }
    t -= 32;
    if (t < 32) {
        int h5 = t >> 4, reg = t & 15;
        *(float*)(wsb + OFF_BSQ + h5 * 64 + reg * 4) = bsc[WOFFi(h5, reg)];
        return;
    }
    t -= 32;
    if (t < 64) {
        int h5 = t >> 5, r = t & 31, reg = r >> 1, comp = r & 1;
        *(float*)(wsb + OFF_WOQ + h5 * 128 + reg * 8 + comp * 4) =
            wout[WOFFi(h5, reg) * 2 + comp];
        return;
    }
}

// pass A: input proj -> mlp20 -> segment-sum. 4 waves/block, 64 rows/wave.
__global__ __launch_bounds__(256, 4) void pass_a(
    const float* __restrict__ md, const float* __restrict__ iobs,
    const float* __restrict__ sig, const char* __restrict__ wsb,
    const int* __restrict__ ids, float* __restrict__ sums) {
    __shared__ __attribute__((aligned(16))) char lfr[2][16384];
    __shared__ __attribute__((aligned(16))) char lbias[7680];
    int lane = threadIdx.x & 63, wv = threadIdx.x >> 6;
    int h5 = lane >> 5;
    int R = blockIdx.x * 256 + wv * 64;
    bool act = (R < N_ROWS);
    int Rb = act ? R : 0;
    int row0 = Rb + (lane & 31), row1 = row0 + 32;

    // issue layer-0 frag stage early
    f32x4 stg[4];
    const uint32_t sc = (uint32_t)(wv * 4096 + lane * 16);
#pragma unroll
    for (int i = 0; i < 4; ++i)
        stg[i] = *(const f32x4*)(wsb + WB + sc + (uint32_t)(i * 1024));
    // stage all biases to LDS (480 x 16B chunks; c*16 == l*384 + o)
    for (int c = threadIdx.x; c < 480; c += 256) {
        int l = c / 24, o = (c % 24) * 16;
        *(f32x4*)(lbias + c * 16) = *(const f32x4*)(wsb + WB + l * LSTR2 + 16384 + o);
    }

    bf16x8 X0[4], X1[4];
    load_xfrags(md, iobs, sig, row0, h5, X0);
    load_xfrags(md, iobs, sig, row1, h5, X1);

    float h0[16], h1[16];
    input_proj32_x2(X0, X1, wsb, OFF_WI, OFF_BIQ, h0, h1, lane, h5);

#pragma unroll
    for (int i = 0; i < 4; ++i)
        *(f32x4*)(&lfr[0][0] + sc + (uint32_t)(i * 1024)) = stg[i];
    __syncthreads();

    mlp20_x2(h0, h1, &lfr[0][0], lbias, wsb, wv, lane, h5);

    if (!act) return;
#pragma unroll
    for (int tile = 0; tile < 2; ++tile) {
        float* h = tile ? h1 : h0;
        int tb = R + tile * 32;
        int rowt = tile ? row1 : row0;
        int id0 = ids[tb];
        bool uni = (id0 == ids[tb + 31]);
        if (uni) {
#pragma unroll
            for (int m = 1; m < 32; m <<= 1) {
#pragma unroll
                for (int i = 0; i < 16; ++i) h[i] += __shfl_xor(h[i], m, 64);
            }
            if ((lane & 31) == 0) {
#pragma unroll
                for (int i = 0; i < 16; ++i)
                    atomicAdd(&sums[id0 * 32 + WOFFi(h5, i)], h[i]);
            }
        } else {
            int id = ids[rowt];
#pragma unroll
            for (int i = 0; i < 16; ++i)
                atomicAdd(&sums[id * 32 + WOFFi(h5, i)], h[i]);
        }
    }
}

__global__ __launch_bounds__(256) void normalize_kernel(float* __restrict__ sums,
                                                        const int* __restrict__ cnts) {
    int t = blockIdx.x * 256 + threadIdx.x;
    if (t < NIMG * WIDTH) {
        int img = t >> 5;
        float cc = (float)max(cnts[img], 1);
        sums[t] = sums[t] / cc;
    }
}

// pass B: input proj + pooled -> mlp20 -> head -> sample
__global__ __launch_bounds__(256, 4) void pass_b(
    const float* __restrict__ md, const char* __restrict__ wsb,
    const float* __restrict__ bout, const int* __restrict__ ids,
    const float* __restrict__ pooled, float* __restrict__ out) {
    __shared__ __attribute__((aligned(16))) char lfr[2][16384];
    __shared__ __attribute__((aligned(16))) char lbias[7680];
    int lane = threadIdx.x & 63, wv = threadIdx.x >> 6;
    int h5 = lane >> 5;
    int R = blockIdx.x * 256 + wv * 64;
    bool act = (R < N_ROWS);
    int Rb = act ? R : 0;
    int row0 = Rb + (lane & 31), row1 = row0 + 32;

    f32x4 stg[4];
    const uint32_t sc = (uint32_t)(wv * 4096 + lane * 16);
#pragma unroll
    for (int i = 0; i < 4; ++i)
        stg[i] = *(const f32x4*)(wsb + WB + sc + (uint32_t)(i * 1024));
    for (int c = threadIdx.x; c < 480; c += 256) {
        int l = c / 24, o = (c % 24) * 16;
        *(f32x4*)(lbias + c * 16) = *(const f32x4*)(wsb + WB + l * LSTR2 + 16384 + o);
    }

    bf16x8 X0[4], X1[4];
    load_xfrags(md, nullptr, nullptr, row0, h5, X0);
    load_xfrags(md, nullptr, nullptr, row1, h5, X1);

    float h0[16], h1[16];
    input_proj32_x2(X0, X1, wsb, OFF_WS, OFF_BSQ, h0, h1, lane, h5);

#pragma unroll
    for (int tile = 0; tile < 2; ++tile) {
        float* h = tile ? h1 : h0;
        int idp = ids[tile ? row1 : row0];
#pragma unroll
        for (int a = 0; a < 4; ++a) {
            f32x4 q = *(const f32x4*)(pooled + idp * 32 + 8 * a + 4 * h5);
#pragma unroll
            for (int i = 0; i < 4; ++i) h[4 * a + i] += q[i];
        }
    }

#pragma unroll
    for (int i = 0; i < 4; ++i)
        *(f32x4*)(&lfr[0][0] + sc + (uint32_t)(i * 1024)) = stg[i];
    __syncthreads();

    mlp20_x2(h0, h1, &lfr[0][0], lbias, wsb, wv, lane, h5);

    if (!act) return;
    f32x4 wq[8];
    {
        const char* wp = wsb + OFF_WOQ + (uint32_t)(h5 * 128);
#pragma unroll
        for (int r = 0; r < 8; ++r) wq[r] = *(const f32x4*)(wp + 16 * r);
    }
#pragma unroll
    for (int tile = 0; tile < 2; ++tile) {
        const float* h = tile ? h1 : h0;
        int row = tile ? row1 : row0;
        float p0 = 0.0f, p1 = 0.0f;
#pragma unroll
        for (int r = 0; r < 8; ++r) {
            p0 = fmaf(h[2 * r], wq[r][0], p0);
            p1 = fmaf(h[2 * r], wq[r][1], p1);
            p0 = fmaf(h[2 * r + 1], wq[r][2], p0);
            p1 = fmaf(h[2 * r + 1], wq[r][3], p1);
        }
        p0 += __shfl_xor(p0, 32, 64);
        p1 += __shfl_xor(p1, 32, 64);
        float loc = p0 + bout[0];
        float pb = p1 + bout[1];
        float scale = fmaxf(pb, 0.0f) + log1pf(expf(-fabsf(pb))) + 1e-12f;
        float lsg = logf(scale);

        float kp = 0.0f;
        float* zrow = out + (size_t)row * MC + h5 * 16;
#pragma unroll 4
        for (int s4 = 0; s4 < 4; ++s4) {
            f32x4 zv;
#pragma unroll
            for (int jj = 0; jj < 4; ++jj) {
                int tt = h5 * 16 + s4 * 4 + jj;
                uint32_t j = (uint32_t)(tt * N_ROWS) + (uint32_t)row;
                float n = bits_to_normal(tf_bits(j));
                float z = fmaf(scale, n, loc);
                zv[jj] = z;
                kp += fmaf(-0.5f, n * n, fabsf(z));
            }
            *(f32x4*)(zrow + s4 * 4) = zv;
        }
        kp += __shfl_xor(kp, 32, 64);
        if (h5 == 0) {
            out[(size_t)N_ROWS * MC + row] =
                0.01f * (kp * (1.0f / 32.0f) - lsg - 0.91893853320467274f + 0.69314718055994531f);
        }
    }
}

extern "C" void kernel_launch(void* const* d_in, const int* in_sizes, int n_in,
                              void* d_out, int out_size, void* d_ws, size_t ws_size,
                              hipStream_t stream) {
    const float* md   = (const float*)d_in[0];
    const float* iobs = (const float*)d_in[1];
    const float* sig  = (const float*)d_in[2];
    const float* wimg = (const float*)d_in[3];
    const float* bimg = (const float*)d_in[4];
    const float* wsc  = (const float*)d_in[5];
    const float* bsc  = (const float*)d_in[6];
    const float* w1   = (const float*)d_in[7];
    const float* b1   = (const float*)d_in[8];
    const float* w2   = (const float*)d_in[9];
    const float* b2   = (const float*)d_in[10];
    const float* wout = (const float*)d_in[11];
    const float* bout = (const float*)d_in[12];
    const int* ids    = (const int*)d_in[13];
    const int* cnts   = (const int*)d_in[14];
    float* out = (float*)d_out;
    char* wsb = (char*)d_ws;
    float* sums = (float*)wsb;

    // 3125 wave-tiles of 64 rows; 4 waves/block -> 782 blocks (tail waves idle)
    const int nblk = 782;
    prep_kernel<<<399, 256, 0, stream>>>(w1, w2, wimg, wsc, b1, b2, bimg, bsc, wout, wsb);
    pass_a<<<nblk, 256, 0, stream>>>(md, iobs, sig, wsb, ids, sums);
    normalize_kernel<<<(NIMG * WIDTH + 255) / 256, 256, 0, stream>>>(sums, cnts);
    pass_b<<<nblk, 256, 0, stream>>>(md, wsb, bout, ids, sums, out);
}

// Round 7
// 353.906 us; speedup vs baseline: 1.1695x; 1.1695x over previous
//
#include <hip/hip_runtime.h>
#include <stdint.h>

#define N_ROWS 200000
#define NIMG   500
#define DMETA  24
#define WIDTH  32
#define HID    64
#define DEPTH  20
#define MC     32

// LDS: m-major per tile. Row stride 68 dwords -> rows 16B-aligned, b128 reads
// near-conflict-free; b32 writes pay 1 conflict cycle each (measured, ~5%).
#define LSTRIDE_F 68
#define TILE_F    (16 * LSTRIDE_F)   // 1088 floats per 16-row tile

// ws layout (bytes):
//   [0, 64000)              : sums (500*32 f32), zeroed by prep
//   [WB + l*LSTR ...)       : per-layer block, l = 0..19:
//       +0     stage1 frags  [t(4)][hi/lo][lane(64)][j(8)] bf16
//       +8192  stage2 frags  [kf(2)][t2(2)][hi/lo][lane][j] bf16
//       +16384 bias1 quads [t(4)][c(16)] f32x4 broadcast of b1[l][16t+c]
//       +17408 bias2 quads [t2(2)][c(16)] f32x4 broadcast of b2[l][16t2+c]
//   [OFF_WIH ...)           : wimg / wscale frag tables (2048 B each)
#define WB    64000
#define LSTR  17920
#define OFF_WIH (WB + DEPTH * LSTR)      // 422400
#define OFF_WIL (OFF_WIH + 2048)
#define OFF_WSH (OFF_WIH + 4096)
#define OFF_WSL (OFF_WIH + 6144)         // end 430592 bytes of ws used

typedef __attribute__((ext_vector_type(8))) short bf16x8;
typedef __attribute__((ext_vector_type(4))) float f32x4;

#define MFMA(a, b, acc) __builtin_amdgcn_mfma_f32_16x16x32_bf16((a), (b), (acc), 0, 0, 0)

__device__ __forceinline__ uint32_t rotl32(uint32_t x, int r) {
    return (x << r) | (x >> (32 - r));
}

// JAX partitionable threefry, key (0,42): bits(j) = x0^x1 of threefry2x32((0,42),(0,j))
__device__ __forceinline__ uint32_t tf_bits(uint32_t j) {
    const uint32_t ks1 = 42u, ks2 = 0x1BD11BDAu ^ 42u;
    uint32_t x0 = 0u, x1 = j + ks1;
#define R4(a,b,c,d) \
    x0 += x1; x1 = rotl32(x1,(a)); x1 ^= x0; \
    x0 += x1; x1 = rotl32(x1,(b)); x1 ^= x0; \
    x0 += x1; x1 = rotl32(x1,(c)); x1 ^= x0; \
    x0 += x1; x1 = rotl32(x1,(d)); x1 ^= x0;
    R4(13,15,26,6)  x0 += ks1; x1 += ks2 + 1u;
    R4(17,29,16,24) x0 += ks2; x1 += 0u + 2u;
    R4(13,15,26,6)                x1 += ks1 + 3u;
    R4(17,29,16,24) x0 += ks1; x1 += ks2 + 4u;
    R4(13,15,26,6)  x0 += ks2; x1 += 0u + 5u;
#undef R4
    return x0 ^ x1;
}

__device__ __forceinline__ float bits_to_normal(uint32_t b) {
    float f = __uint_as_float((b >> 9) | 0x3f800000u) - 1.0f;
    const float lo = -0.99999994f;
    float u = fmaxf(lo, f * 2.0f + lo);
    return 1.41421356f * erfinvf(u);
}

// split (prep, scalar): round-half-up hi, truncated lo. |x - hi - lo| <~ 2^-16 |x|
__device__ __forceinline__ void split1(float x, short& hi, short& lo) {
    uint32_t b = __float_as_uint(x);
    uint32_t a = b + 0x8000u;
    hi = (short)(a >> 16);
    float r = x - __uint_as_float(a & 0xFFFF0000u);
    lo = (short)(__float_as_uint(r) >> 16);
}

// vector split+pack: 8 f32 -> bf16x8 hi, bf16x8 lo via v_cvt_pk_bf16_f32
// (6 VALU per f32 pair: cvt_pk, shl, and, 2x sub, cvt_pk)
__device__ __forceinline__ void split8p(const float* x, bf16x8& hi, bf16x8& lo) {
    uint32_t hu[4], lu[4];
#pragma unroll
    for (int p = 0; p < 4; ++p) {
        float x0 = x[2 * p], x1 = x[2 * p + 1];
        uint32_t h;
        asm("v_cvt_pk_bf16_f32 %0, %1, %2" : "=v"(h) : "v"(x0), "v"(x1));
        float r0 = x0 - __uint_as_float(h << 16);
        float r1 = x1 - __uint_as_float(h & 0xFFFF0000u);
        uint32_t l;
        asm("v_cvt_pk_bf16_f32 %0, %1, %2" : "=v"(l) : "v"(r0), "v"(r1));
        hu[p] = h;
        lu[p] = l;
    }
    __builtin_memcpy(&hi, hu, 16);
    __builtin_memcpy(&lo, lu, 16);
}

// single-precision pack: 8 f32 -> bf16x8 (RNE), 1 VALU per pair
__device__ __forceinline__ void cvt8p(const float* x, bf16x8& hi) {
    uint32_t hu[4];
#pragma unroll
    for (int p = 0; p < 4; ++p) {
        uint32_t h;
        asm("v_cvt_pk_bf16_f32 %0, %1, %2" : "=v"(h) : "v"(x[2 * p]), "v"(x[2 * p + 1]));
        hu[p] = h;
    }
    __builtin_memcpy(&hi, hu, 16);
}

// 20 residual blocks, two independent 16-row tiles per wave.
// Stage 1 AND stage 2: activations single RNE bf16 (A-operand), weights hi/lo
// (2 MFMA terms). Residual trunk stays f32 in registers. Bias quads are MFMA
// C-operands.
__device__ __forceinline__ void mlp20_x2(
    float* hC0, float* hC1, float* smw, const char* __restrict__ wsb,
    int lane, int q, int c) {
    const int ldsR = c * LSTRIDE_F + q * 8;       // read base (row m=c), dwords
    const int ldsW = q * 4 * LSTRIDE_F + c;       // write base (m=4q, k=c), dwords
    uint32_t offA  = (uint32_t)(WB + (lane << 4));    // stage1 t=0,1
    uint32_t offB  = offA + 4096u;                     // stage1 t=2,3
    uint32_t offC  = offA + 8192u;                     // stage2 kf=0
    uint32_t offD  = offA + 12288u;                    // stage2 kf=1
    uint32_t offB1 = (uint32_t)(WB + 16384 + (c << 4));
    uint32_t offB2 = (uint32_t)(WB + 17408 + (c << 4));
#pragma unroll 1
    for (int l = 0; l < DEPTH; ++l) {
        // RT1: residual h (C-layout regs) -> LDS m-major, b32 stores
#pragma unroll
        for (int t = 0; t < 2; ++t)
#pragma unroll
            for (int r = 0; r < 4; ++r) {
                smw[ldsW + r * LSTRIDE_F + t * 16] = hC0[t * 4 + r];
                smw[TILE_F + ldsW + r * LSTRIDE_F + t * 16] = hC1[t * 4 + r];
            }
        f32x4 v0 = *(const f32x4*)(smw + ldsR);
        f32x4 v1 = *(const f32x4*)(smw + ldsR + 4);
        f32x4 u0 = *(const f32x4*)(smw + TILE_F + ldsR);
        f32x4 u1 = *(const f32x4*)(smw + TILE_F + ldsR + 4);
        float a0[8], a1[8];
#pragma unroll
        for (int j = 0; j < 4; ++j) {
            a0[j] = v0[j]; a0[4 + j] = v1[j];
            a1[j] = u0[j]; a1[4 + j] = u1[j];
        }
        bf16x8 ah0, ah1;
        cvt8p(a0, ah0);
        cvt8p(a1, ah1);
        // stage 1: H1 = relu(h @ W1 + b1); bias quad is the MFMA C-operand
        float C1v0[16], C1v1[16];
#pragma unroll
        for (int t = 0; t < 4; ++t) {
            uint32_t o = (t < 2 ? offA : offB) + (uint32_t)((t & 1) << 11);
            bf16x8 bh = *(const bf16x8*)(wsb + o);
            bf16x8 bl = *(const bf16x8*)(wsb + o + 1024);
            f32x4 b1q = *(const f32x4*)(wsb + offB1 + (uint32_t)(t << 8));
            f32x4 acc = MFMA(ah0, bh, b1q);
            acc = MFMA(ah0, bl, acc);
            f32x4 acd = MFMA(ah1, bh, b1q);
            acd = MFMA(ah1, bl, acd);
#pragma unroll
            for (int r = 0; r < 4; ++r) {
                C1v0[t * 4 + r] = fmaxf(acc[r], 0.0f);
                C1v1[t * 4 + r] = fmaxf(acd[r], 0.0f);
            }
        }
        // RT2: H1 -> LDS m-major
#pragma unroll
        for (int t = 0; t < 4; ++t)
#pragma unroll
            for (int r = 0; r < 4; ++r) {
                smw[ldsW + r * LSTRIDE_F + t * 16] = C1v0[t * 4 + r];
                smw[TILE_F + ldsW + r * LSTRIDE_F + t * 16] = C1v1[t * 4 + r];
            }
        // stage 2: h = h + H1 @ W2 + b2 ; residual + bias quad in acc init
        f32x4 b2q0 = *(const f32x4*)(wsb + offB2);
        f32x4 b2q1 = *(const f32x4*)(wsb + offB2 + 256u);
        f32x4 acc0[2], acc1[2];
#pragma unroll
        for (int r = 0; r < 4; ++r) {
            acc0[0][r] = hC0[r] + b2q0[r];
            acc0[1][r] = hC0[4 + r] + b2q1[r];
            acc1[0][r] = hC1[r] + b2q0[r];
            acc1[1][r] = hC1[4 + r] + b2q1[r];
        }
#pragma unroll
        for (int kf = 0; kf < 2; ++kf) {
            f32x4 e0a = *(const f32x4*)(smw + ldsR + kf * 32);
            f32x4 e0b = *(const f32x4*)(smw + ldsR + kf * 32 + 4);
            f32x4 e1a = *(const f32x4*)(smw + TILE_F + ldsR + kf * 32);
            f32x4 e1b = *(const f32x4*)(smw + TILE_F + ldsR + kf * 32 + 4);
            float e0[8], e1[8];
#pragma unroll
            for (int j = 0; j < 4; ++j) {
                e0[j] = e0a[j]; e0[4 + j] = e0b[j];
                e1[j] = e1a[j]; e1[4 + j] = e1b[j];
            }
            bf16x8 xh0, xh1;
            cvt8p(e0, xh0);
            cvt8p(e1, xh1);
#pragma unroll
            for (int t2 = 0; t2 < 2; ++t2) {
                uint32_t o = (kf ? offD : offC) + (uint32_t)(t2 << 11);
                bf16x8 bh = *(const bf16x8*)(wsb + o);
                bf16x8 bl = *(const bf16x8*)(wsb + o + 1024);
                acc0[t2] = MFMA(xh0, bh, acc0[t2]);
                acc0[t2] = MFMA(xh0, bl, acc0[t2]);
                acc1[t2] = MFMA(xh1, bh, acc1[t2]);
                acc1[t2] = MFMA(xh1, bl, acc1[t2]);
            }
        }
#pragma unroll
        for (int t2 = 0; t2 < 2; ++t2)
#pragma unroll
            for (int r = 0; r < 4; ++r) {
                hC0[t2 * 4 + r] = acc0[t2][r];
                hC1[t2 * 4 + r] = acc1[t2][r];
            }
        offA += LSTR; offB += LSTR; offC += LSTR; offD += LSTR;
        offB1 += LSTR; offB2 += LSTR;
    }
}

// input projection for one 16-row tile -> hC (C-layout); bias in acc init.
// Kept at full hi/lo on activations (once per pass, negligible cost).
__device__ __forceinline__ void input_proj(
    const bf16x8& ah, const bf16x8& al, const short* __restrict__ wfh,
    const short* __restrict__ wfl, const float* __restrict__ bias,
    float* hC, int lane, int c) {
#pragma unroll
    for (int t = 0; t < 2; ++t) {
        bf16x8 bh = *(const bf16x8*)(wfh + ((t << 9) + (lane << 3)));
        bf16x8 bl = *(const bf16x8*)(wfl + ((t << 9) + (lane << 3)));
        float bb = bias[16 * t + c];
        f32x4 acc = {bb, bb, bb, bb};
        acc = MFMA(ah, bh, acc); acc = MFMA(ah, bl, acc); acc = MFMA(al, bh, acc);
#pragma unroll
        for (int r = 0; r < 4; ++r) hC[t * 4 + r] = acc[r];
    }
}

// prep: zero sums; per-layer weight blocks + broadcast bias quads; wimg/wscale.
__global__ __launch_bounds__(256) void prep_kernel(
    const float* __restrict__ w1, const float* __restrict__ w2,
    const float* __restrict__ wimg, const float* __restrict__ wsc,
    const float* __restrict__ b1, const float* __restrict__ b2,
    char* __restrict__ wsb) {
    int t = blockIdx.x * 256 + threadIdx.x;
    float* sums = (float*)wsb;
    if (t < 16000) { sums[t] = 0.0f; return; }
    t -= 16000;
    if (t < 40960) {  // stage1 frags: [l][t][lane][j]
        int l = t >> 11, r = t & 2047, tt = r >> 9, r2 = r & 511;
        int lane = r2 >> 3, j = r2 & 7;
        int k = (lane >> 4) * 8 + j, n = 16 * tt + (lane & 15);
        short h, lo;
        split1(w1[l * 2048 + k * 64 + n], h, lo);
        char* base = wsb + WB + l * LSTR + tt * 2048 + 2 * r2;
        *(short*)(base) = h;
        *(short*)(base + 1024) = lo;
        return;
    }
    t -= 40960;
    if (t < 40960) {  // stage2 frags: [l][kf][t2][lane][j]
        int l = t >> 11, r = t & 2047, kf = r >> 10, r2 = r & 1023;
        int t2 = r2 >> 9, r3 = r2 & 511, lane = r3 >> 3, j = r3 & 7;
        int k = kf * 32 + (lane >> 4) * 8 + j, n = 16 * t2 + (lane & 15);
        short h, lo;
        split1(w2[l * 2048 + k * 32 + n], h, lo);
        char* base = wsb + WB + l * LSTR + 8192 + (kf * 2 + t2) * 2048 + 2 * r3;
        *(short*)(base) = h;
        *(short*)(base + 1024) = lo;
        return;
    }
    t -= 40960;
    if (t < 1024) {  // wimg frags (K padded 26->32)
        int tt = t >> 9, r = t & 511, lane = r >> 3, j = r & 7;
        int k = (lane >> 4) * 8 + j, n = 16 * tt + (lane & 15);
        float v = (k < 26) ? wimg[k * 32 + n] : 0.0f;
        short h, lo;
        split1(v, h, lo);
        ((short*)(wsb + OFF_WIH))[t] = h;
        ((short*)(wsb + OFF_WIL))[t] = lo;
        return;
    }
    t -= 1024;
    if (t < 1024) {  // wscale frags (K padded 24->32)
        int tt = t >> 9, r = t & 511, lane = r >> 3, j = r & 7;
        int k = (lane >> 4) * 8 + j, n = 16 * tt + (lane & 15);
        float v = (k < 24) ? wsc[k * 32 + n] : 0.0f;
        short h, lo;
        split1(v, h, lo);
        ((short*)(wsb + OFF_WSH))[t] = h;
        ((short*)(wsb + OFF_WSL))[t] = lo;
        return;
    }
    t -= 1024;
    if (t < 5120) {  // bias1 quads: [l][t(4)][c(16)] x4 floats, bcast b1[l][16t+c]
        int l = t >> 8, r = t & 255;
        int tt = r >> 6, cc = (r >> 2) & 15;
        *(float*)(wsb + WB + l * LSTR + 16384 + 4 * r) = b1[l * 64 + tt * 16 + cc];
        return;
    }
    t -= 5120;
    if (t < 2560) {  // bias2 quads: [l][t2(2)][c(16)] x4 floats, bcast b2[l][16t2+c]
        int l = t >> 7, r = t & 127;
        int t2 = r >> 6, cc = (r >> 2) & 15;
        *(float*)(wsb + WB + l * LSTR + 17408 + 4 * r) = b2[l * 32 + t2 * 16 + cc];
        return;
    }
}

// load A-frag of X[16,32] for rows base..base+15 (cols: 24 md, iobs, sig, pad)
__device__ __forceinline__ void load_xfrag(
    const float* __restrict__ md, const float* __restrict__ iobs,
    const float* __restrict__ sig, int base, int q, int c,
    bf16x8& ah, bf16x8& al) {
    float xa[8];
    if (q < 3) {
        const f32x4* rp = (const f32x4*)(md + (size_t)(base + c) * DMETA + q * 8);
        f32x4 v0 = rp[0], v1 = rp[1];
#pragma unroll
        for (int j = 0; j < 4; ++j) { xa[j] = v0[j]; xa[4 + j] = v1[j]; }
    } else {
        xa[0] = iobs ? iobs[base + c] : 0.0f;
        xa[1] = sig ? sig[base + c] : 0.0f;
#pragma unroll
        for (int j = 2; j < 8; ++j) xa[j] = 0.0f;
    }
    split8p(xa, ah, al);
}

// pass A: input proj -> mlp20 (2 tiles/wave) -> segment-sum (uniform-id fast path)
__global__ __launch_bounds__(128, 4) void pass_a(
    const float* __restrict__ md, const float* __restrict__ iobs,
    const float* __restrict__ sig, const float* __restrict__ bimg,
    const char* __restrict__ wsb, const int* __restrict__ ids,
    float* __restrict__ sums) {
    __shared__ __attribute__((aligned(16))) float smat[2][2 * TILE_F];
    int lane = threadIdx.x & 63, w = threadIdx.x >> 6;
    int q = lane >> 4, c = lane & 15;
    int i0 = (blockIdx.x * 2 + w) * 32;
    float* smw = &smat[w][0];

    bf16x8 ah0, al0, ah1, al1;
    load_xfrag(md, iobs, sig, i0, q, c, ah0, al0);
    load_xfrag(md, iobs, sig, i0 + 16, q, c, ah1, al1);

    float hC0[8], hC1[8];
    input_proj(ah0, al0, (const short*)(wsb + OFF_WIH), (const short*)(wsb + OFF_WIL),
               bimg, hC0, lane, c);
    input_proj(ah1, al1, (const short*)(wsb + OFF_WIH), (const short*)(wsb + OFF_WIL),
               bimg, hC1, lane, c);

    mlp20_x2(hC0, hC1, smw, wsb, lane, q, c);

#pragma unroll
    for (int tile = 0; tile < 2; ++tile) {
        const float* hC = tile ? hC1 : hC0;
        int tb = i0 + tile * 16;
        bool uni = (ids[tb] == ids[tb + 15]);   // wave-uniform branch
        if (uni) {
            int id = ids[tb];
#pragma unroll
            for (int t = 0; t < 2; ++t) {
                float s = (hC[t * 4 + 0] + hC[t * 4 + 1]) + (hC[t * 4 + 2] + hC[t * 4 + 3]);
                s += __shfl_xor(s, 16, 64);
                s += __shfl_xor(s, 32, 64);
                if (q == 0) atomicAdd(&sums[id * 32 + 16 * t + c], s);
            }
        } else {
            int idv[4];
#pragma unroll
            for (int r = 0; r < 4; ++r) idv[r] = ids[tb + q * 4 + r];
#pragma unroll
            for (int t = 0; t < 2; ++t)
#pragma unroll
                for (int r = 0; r < 4; ++r)
                    atomicAdd(&sums[idv[r] * 32 + 16 * t + c], hC[t * 4 + r]);
        }
    }
}

__global__ __launch_bounds__(256) void normalize_kernel(float* __restrict__ sums,
                                                        const int* __restrict__ cnts) {
    int t = blockIdx.x * 256 + threadIdx.x;
    if (t < NIMG * WIDTH) {
        int img = t >> 5;
        float cc = (float)max(cnts[img], 1);
        sums[t] = sums[t] / cc;
    }
}

// pass B: input proj + pooled -> mlp20 (2 tiles/wave) -> head -> sample -> z, kl
__global__ __launch_bounds__(128, 4) void pass_b(
    const float* __restrict__ md, const float* __restrict__ bsc,
    const char* __restrict__ wsb, const float* __restrict__ wout,
    const float* __restrict__ bout, const int* __restrict__ ids,
    const float* __restrict__ pooled, float* __restrict__ out) {
    __shared__ __attribute__((aligned(16))) float smat[2][2 * TILE_F];
    __shared__ float sls[2][64];
    int lane = threadIdx.x & 63, w = threadIdx.x >> 6;
    int q = lane >> 4, c = lane & 15;
    int i0 = (blockIdx.x * 2 + w) * 32;
    float* smw = &smat[w][0];

    bf16x8 ah0, al0, ah1, al1;
    load_xfrag(md, nullptr, nullptr, i0, q, c, ah0, al0);
    load_xfrag(md, nullptr, nullptr, i0 + 16, q, c, ah1, al1);

    float hC0[8], hC1[8];
    input_proj(ah0, al0, (const short*)(wsb + OFF_WSH), (const short*)(wsb + OFF_WSL),
               bsc, hC0, lane, c);
    input_proj(ah1, al1, (const short*)(wsb + OFF_WSH), (const short*)(wsb + OFF_WSL),
               bsc, hC1, lane, c);
    // add pooled[id] per row
#pragma unroll
    for (int tile = 0; tile < 2; ++tile) {
        float* hC = tile ? hC1 : hC0;
        int tb = i0 + tile * 16;
        int idv[4];
#pragma unroll
        for (int r = 0; r < 4; ++r) idv[r] = ids[tb + q * 4 + r];
#pragma unroll
        for (int t = 0; t < 2; ++t)
#pragma unroll
            for (int r = 0; r < 4; ++r)
                hC[t * 4 + r] += pooled[idv[r] * 32 + 16 * t + c];
    }

    mlp20_x2(hC0, hC1, smw, wsb, lane, q, c);

    // head per tile: params = h @ wout + bout (reduce across the 16 c-lanes)
    float wo0[2], wo1[2];
#pragma unroll
    for (int t = 0; t < 2; ++t) {
        float2 wv = ((const float2*)wout)[16 * t + c];
        wo0[t] = wv.x; wo1[t] = wv.y;
    }
#pragma unroll
    for (int tile = 0; tile < 2; ++tile) {
        const float* hC = tile ? hC1 : hC0;
        float p0r[4], p1r[4];
#pragma unroll
        for (int r = 0; r < 4; ++r) {
            p0r[r] = hC[r] * wo0[0] + hC[4 + r] * wo0[1];
            p1r[r] = hC[r] * wo1[0] + hC[4 + r] * wo1[1];
        }
#pragma unroll
        for (int m = 1; m < 16; m <<= 1) {
#pragma unroll
            for (int r = 0; r < 4; ++r) {
                p0r[r] += __shfl_xor(p0r[r], m, 64);
                p1r[r] += __shfl_xor(p1r[r], m, 64);
            }
        }
        if (c == 0) {
#pragma unroll
            for (int r = 0; r < 4; ++r) {
                float loc = p0r[r] + bout[0];
                float pb = p1r[r] + bout[1];
                float scale = fmaxf(pb, 0.0f) + log1pf(expf(-fabsf(pb))) + 1e-12f;
                sls[w][tile * 16 + q * 4 + r] = loc;
                sls[w][32 + tile * 16 + q * 4 + r] = scale;
            }
        }
    }

    // sampling: lane covers row (i0 + lane&31), draws half*16..+15
    int ro = lane & 31, half = lane >> 5;
    int row = i0 + ro;
    float L = sls[w][ro];
    float S = sls[w][32 + ro];
    float lsg = logf(S);
    float kp = 0.0f;
    float* zrow = out + (size_t)row * MC + half * 16;
#pragma unroll 4
    for (int s4 = 0; s4 < 4; ++s4) {
        f32x4 zv;
#pragma unroll
        for (int jj = 0; jj < 4; ++jj) {
            int t = half * 16 + s4 * 4 + jj;
            uint32_t j = (uint32_t)(t * N_ROWS) + (uint32_t)row;
            float n = bits_to_normal(tf_bits(j));
            float z = fmaf(S, n, L);
            zv[jj] = z;
            kp += fmaf(-0.5f, n * n, fabsf(z));
        }
        *(f32x4*)(zrow + s4 * 4) = zv;
    }
    kp += __shfl_xor(kp, 32, 64);
    if (half == 0) {
        out[(size_t)N_ROWS * MC + row] =
            0.01f * (kp * (1.0f / 32.0f) - lsg - 0.91893853320467274f + 0.69314718055994531f);
    }
}

extern "C" void kernel_launch(void* const* d_in, const int* in_sizes, int n_in,
                              void* d_out, int out_size, void* d_ws, size_t ws_size,
                              hipStream_t stream) {
    const float* md   = (const float*)d_in[0];
    const float* iobs = (const float*)d_in[1];
    const float* sig  = (const float*)d_in[2];
    const float* wimg = (const float*)d_in[3];
    const float* bimg = (const float*)d_in[4];
    const float* wsc  = (const float*)d_in[5];
    const float* bsc  = (const float*)d_in[6];
    const float* w1   = (const float*)d_in[7];
    const float* b1   = (const float*)d_in[8];
    const float* w2   = (const float*)d_in[9];
    const float* b2   = (const float*)d_in[10];
    const float* wout = (const float*)d_in[11];
    const float* bout = (const float*)d_in[12];
    const int* ids    = (const int*)d_in[13];
    const int* cnts   = (const int*)d_in[14];
    float* out = (float*)d_out;
    char* wsb = (char*)d_ws;
    float* sums = (float*)wsb;

    const int nblk = N_ROWS / 64;  // 3125 blocks x 2 waves x 32 rows, exact
    prep_kernel<<<421, 256, 0, stream>>>(w1, w2, wimg, wsc, b1, b2, wsb);
    pass_a<<<nblk, 128, 0, stream>>>(md, iobs, sig, bimg, wsb, ids, sums);
    normalize_kernel<<<(NIMG * WIDTH + 255) / 256, 256, 0, stream>>>(sums, cnts);
    pass_b<<<nblk, 128, 0, stream>>>(md, bsc, wsb, wout, bout, ids, sums, out);
}

// Round 8
// 321.391 us; speedup vs baseline: 1.2879x; 1.1012x over previous
//
#include <hip/hip_runtime.h>
#include <stdint.h>

#define N_ROWS 200000
#define NIMG   500
#define DMETA  24
#define WIDTH  32
#define HID    64
#define DEPTH  20
#define MC     32

// LDS: m-major, ONE tile-buffer per wave, tiles time-multiplexed through it
// (per-wave DS ops are in-order -> WAR between tile0 reads and tile1 writes is
// free). 9.2KB/block -> entire 12.2-blocks/CU grid co-resident in one round.
#define LSTRIDE_F 68
#define TILE_F    (16 * LSTRIDE_F)   // 1088 floats per tile buffer

// ws layout (bytes): same as rounds 3/7.
#define WB    64000
#define LSTR  17920
#define OFF_WIH (WB + DEPTH * LSTR)      // 422400
#define OFF_WIL (OFF_WIH + 2048)
#define OFF_WSH (OFF_WIH + 4096)
#define OFF_WSL (OFF_WIH + 6144)         // end 430592 bytes of ws used

typedef __attribute__((ext_vector_type(8))) short bf16x8;
typedef __attribute__((ext_vector_type(4))) float f32x4;

#define MFMA(a, b, acc) __builtin_amdgcn_mfma_f32_16x16x32_bf16((a), (b), (acc), 0, 0, 0)

__device__ __forceinline__ uint32_t rotl32(uint32_t x, int r) {
    return (x << r) | (x >> (32 - r));
}

// JAX partitionable threefry, key (0,42): bits(j) = x0^x1 of threefry2x32((0,42),(0,j))
__device__ __forceinline__ uint32_t tf_bits(uint32_t j) {
    const uint32_t ks1 = 42u, ks2 = 0x1BD11BDAu ^ 42u;
    uint32_t x0 = 0u, x1 = j + ks1;
#define R4(a,b,c,d) \
    x0 += x1; x1 = rotl32(x1,(a)); x1 ^= x0; \
    x0 += x1; x1 = rotl32(x1,(b)); x1 ^= x0; \
    x0 += x1; x1 = rotl32(x1,(c)); x1 ^= x0; \
    x0 += x1; x1 = rotl32(x1,(d)); x1 ^= x0;
    R4(13,15,26,6)  x0 += ks1; x1 += ks2 + 1u;
    R4(17,29,16,24) x0 += ks2; x1 += 0u + 2u;
    R4(13,15,26,6)                x1 += ks1 + 3u;
    R4(17,29,16,24) x0 += ks1; x1 += ks2 + 4u;
    R4(13,15,26,6)  x0 += ks2; x1 += 0u + 5u;
#undef R4
    return x0 ^ x1;
}

__device__ __forceinline__ float bits_to_normal(uint32_t b) {
    float f = __uint_as_float((b >> 9) | 0x3f800000u) - 1.0f;
    const float lo = -0.99999994f;
    float u = fmaxf(lo, f * 2.0f + lo);
    return 1.41421356f * erfinvf(u);
}

// split (prep, scalar): round-half-up hi, truncated lo. |x - hi - lo| <~ 2^-16 |x|
__device__ __forceinline__ void split1(float x, short& hi, short& lo) {
    uint32_t b = __float_as_uint(x);
    uint32_t a = b + 0x8000u;
    hi = (short)(a >> 16);
    float r = x - __uint_as_float(a & 0xFFFF0000u);
    lo = (short)(__float_as_uint(r) >> 16);
}

// vector split+pack: 8 f32 -> bf16x8 hi, bf16x8 lo via v_cvt_pk_bf16_f32
__device__ __forceinline__ void split8p(const float* x, bf16x8& hi, bf16x8& lo) {
    uint32_t hu[4], lu[4];
#pragma unroll
    for (int p = 0; p < 4; ++p) {
        float x0 = x[2 * p], x1 = x[2 * p + 1];
        uint32_t h;
        asm("v_cvt_pk_bf16_f32 %0, %1, %2" : "=v"(h) : "v"(x0), "v"(x1));
        float r0 = x0 - __uint_as_float(h << 16);
        float r1 = x1 - __uint_as_float(h & 0xFFFF0000u);
        uint32_t l;
        asm("v_cvt_pk_bf16_f32 %0, %1, %2" : "=v"(l) : "v"(r0), "v"(r1));
        hu[p] = h;
        lu[p] = l;
    }
    __builtin_memcpy(&hi, hu, 16);
    __builtin_memcpy(&lo, lu, 16);
}

// single-precision pack: 8 f32 -> bf16x8 (RNE), 1 VALU per pair
__device__ __forceinline__ void cvt8p(const float* x, bf16x8& hi) {
    uint32_t hu[4];
#pragma unroll
    for (int p = 0; p < 4; ++p) {
        uint32_t h;
        asm("v_cvt_pk_bf16_f32 %0, %1, %2" : "=v"(h) : "v"(x[2 * p]), "v"(x[2 * p + 1]));
        hu[p] = h;
    }
    __builtin_memcpy(&hi, hu, 16);
}

// 20 residual blocks, two independent 16-row tiles per wave, ONE LDS buffer
// time-multiplexed between tiles. Activations single RNE bf16 (A-operand),
// weights hi/lo (2 MFMA terms). Residual trunk f32 in registers.
__device__ __forceinline__ void mlp20_x2(
    float* hC0, float* hC1, float* smw, const char* __restrict__ wsb,
    int lane, int q, int c) {
    const int ldsR = c * LSTRIDE_F + q * 8;       // read base (row m=c), dwords
    const int ldsW = q * 4 * LSTRIDE_F + c;       // write base (m=4q, k=c), dwords
    uint32_t offA  = (uint32_t)(WB + (lane << 4));    // stage1 t=0,1
    uint32_t offB  = offA + 4096u;                     // stage1 t=2,3
    uint32_t offC  = offA + 8192u;                     // stage2 kf=0
    uint32_t offD  = offA + 12288u;                    // stage2 kf=1
    uint32_t offB1 = (uint32_t)(WB + 16384 + (c << 4));
    uint32_t offB2 = (uint32_t)(WB + 17408 + (c << 4));
#pragma unroll 1
    for (int l = 0; l < DEPTH; ++l) {
        // RT1 tile0: h -> LDS -> A-frag (bf16)
        float a0[8], a1[8];
#pragma unroll
        for (int t = 0; t < 2; ++t)
#pragma unroll
            for (int r = 0; r < 4; ++r)
                smw[ldsW + r * LSTRIDE_F + t * 16] = hC0[t * 4 + r];
        {
            f32x4 v0 = *(const f32x4*)(smw + ldsR);
            f32x4 v1 = *(const f32x4*)(smw + ldsR + 4);
#pragma unroll
            for (int j = 0; j < 4; ++j) { a0[j] = v0[j]; a0[4 + j] = v1[j]; }
        }
        // RT1 tile1 (same buffer; per-wave DS in-order keeps WAR safe)
#pragma unroll
        for (int t = 0; t < 2; ++t)
#pragma unroll
            for (int r = 0; r < 4; ++r)
                smw[ldsW + r * LSTRIDE_F + t * 16] = hC1[t * 4 + r];
        {
            f32x4 u0 = *(const f32x4*)(smw + ldsR);
            f32x4 u1 = *(const f32x4*)(smw + ldsR + 4);
#pragma unroll
            for (int j = 0; j < 4; ++j) { a1[j] = u0[j]; a1[4 + j] = u1[j]; }
        }
        bf16x8 ah0, ah1;
        cvt8p(a0, ah0);
        cvt8p(a1, ah1);
        // stage 1: H1 = relu(h @ W1 + b1); bias quad is the MFMA C-operand
        float C1v0[16], C1v1[16];
#pragma unroll
        for (int t = 0; t < 4; ++t) {
            uint32_t o = (t < 2 ? offA : offB) + (uint32_t)((t & 1) << 11);
            bf16x8 bh = *(const bf16x8*)(wsb + o);
            bf16x8 bl = *(const bf16x8*)(wsb + o + 1024);
            f32x4 b1q = *(const f32x4*)(wsb + offB1 + (uint32_t)(t << 8));
            f32x4 acc = MFMA(ah0, bh, b1q);
            acc = MFMA(ah0, bl, acc);
            f32x4 acd = MFMA(ah1, bh, b1q);
            acd = MFMA(ah1, bl, acd);
#pragma unroll
            for (int r = 0; r < 4; ++r) {
                C1v0[t * 4 + r] = fmaxf(acc[r], 0.0f);
                C1v1[t * 4 + r] = fmaxf(acd[r], 0.0f);
            }
        }
        // RT2 tile0: H1 -> LDS -> both kf A-frags
        bf16x8 xh0[2], xh1[2];
#pragma unroll
        for (int t = 0; t < 4; ++t)
#pragma unroll
            for (int r = 0; r < 4; ++r)
                smw[ldsW + r * LSTRIDE_F + t * 16] = C1v0[t * 4 + r];
#pragma unroll
        for (int kf = 0; kf < 2; ++kf) {
            f32x4 ea = *(const f32x4*)(smw + ldsR + kf * 32);
            f32x4 eb = *(const f32x4*)(smw + ldsR + kf * 32 + 4);
            float e[8];
#pragma unroll
            for (int j = 0; j < 4; ++j) { e[j] = ea[j]; e[4 + j] = eb[j]; }
            cvt8p(e, xh0[kf]);
        }
        // RT2 tile1
#pragma unroll
        for (int t = 0; t < 4; ++t)
#pragma unroll
            for (int r = 0; r < 4; ++r)
                smw[ldsW + r * LSTRIDE_F + t * 16] = C1v1[t * 4 + r];
#pragma unroll
        for (int kf = 0; kf < 2; ++kf) {
            f32x4 ea = *(const f32x4*)(smw + ldsR + kf * 32);
            f32x4 eb = *(const f32x4*)(smw + ldsR + kf * 32 + 4);
            float e[8];
#pragma unroll
            for (int j = 0; j < 4; ++j) { e[j] = ea[j]; e[4 + j] = eb[j]; }
            cvt8p(e, xh1[kf]);
        }
        // stage 2: h = h + H1 @ W2 + b2 ; residual + bias quad in acc init
        f32x4 b2q0 = *(const f32x4*)(wsb + offB2);
        f32x4 b2q1 = *(const f32x4*)(wsb + offB2 + 256u);
        f32x4 acc0[2], acc1[2];
#pragma unroll
        for (int r = 0; r < 4; ++r) {
            acc0[0][r] = hC0[r] + b2q0[r];
            acc0[1][r] = hC0[4 + r] + b2q1[r];
            acc1[0][r] = hC1[r] + b2q0[r];
            acc1[1][r] = hC1[4 + r] + b2q1[r];
        }
#pragma unroll
        for (int kf = 0; kf < 2; ++kf) {
#pragma unroll
            for (int t2 = 0; t2 < 2; ++t2) {
                uint32_t o = (kf ? offD : offC) + (uint32_t)(t2 << 11);
                bf16x8 bh = *(const bf16x8*)(wsb + o);
                bf16x8 bl = *(const bf16x8*)(wsb + o + 1024);
                acc0[t2] = MFMA(xh0[kf], bh, acc0[t2]);
                acc0[t2] = MFMA(xh0[kf], bl, acc0[t2]);
                acc1[t2] = MFMA(xh1[kf], bh, acc1[t2]);
                acc1[t2] = MFMA(xh1[kf], bl, acc1[t2]);
            }
        }
#pragma unroll
        for (int t2 = 0; t2 < 2; ++t2)
#pragma unroll
            for (int r = 0; r < 4; ++r) {
                hC0[t2 * 4 + r] = acc0[t2][r];
                hC1[t2 * 4 + r] = acc1[t2][r];
            }
        offA += LSTR; offB += LSTR; offC += LSTR; offD += LSTR;
        offB1 += LSTR; offB2 += LSTR;
    }
}

// input projection for one 16-row tile -> hC (C-layout); bias in acc init.
__device__ __forceinline__ void input_proj(
    const bf16x8& ah, const bf16x8& al, const short* __restrict__ wfh,
    const short* __restrict__ wfl, const float* __restrict__ bias,
    float* hC, int lane, int c) {
#pragma unroll
    for (int t = 0; t < 2; ++t) {
        bf16x8 bh = *(const bf16x8*)(wfh + ((t << 9) + (lane << 3)));
        bf16x8 bl = *(const bf16x8*)(wfl + ((t << 9) + (lane << 3)));
        float bb = bias[16 * t + c];
        f32x4 acc = {bb, bb, bb, bb};
        acc = MFMA(ah, bh, acc); acc = MFMA(ah, bl, acc); acc = MFMA(al, bh, acc);
#pragma unroll
        for (int r = 0; r < 4; ++r) hC[t * 4 + r] = acc[r];
    }
}

// prep: zero sums; per-layer weight blocks + broadcast bias quads; wimg/wscale.
__global__ __launch_bounds__(256) void prep_kernel(
    const float* __restrict__ w1, const float* __restrict__ w2,
    const float* __restrict__ wimg, const float* __restrict__ wsc,
    const float* __restrict__ b1, const float* __restrict__ b2,
    char* __restrict__ wsb) {
    int t = blockIdx.x * 256 + threadIdx.x;
    float* sums = (float*)wsb;
    if (t < 16000) { sums[t] = 0.0f; return; }
    t -= 16000;
    if (t < 40960) {  // stage1 frags: [l][t][lane][j]
        int l = t >> 11, r = t & 2047, tt = r >> 9, r2 = r & 511;
        int lane = r2 >> 3, j = r2 & 7;
        int k = (lane >> 4) * 8 + j, n = 16 * tt + (lane & 15);
        short h, lo;
        split1(w1[l * 2048 + k * 64 + n], h, lo);
        char* base = wsb + WB + l * LSTR + tt * 2048 + 2 * r2;
        *(short*)(base) = h;
        *(short*)(base + 1024) = lo;
        return;
    }
    t -= 40960;
    if (t < 40960) {  // stage2 frags: [l][kf][t2][lane][j]
        int l = t >> 11, r = t & 2047, kf = r >> 10, r2 = r & 1023;
        int t2 = r2 >> 9, r3 = r2 & 511, lane = r3 >> 3, j = r3 & 7;
        int k = kf * 32 + (lane >> 4) * 8 + j, n = 16 * t2 + (lane & 15);
        short h, lo;
        split1(w2[l * 2048 + k * 32 + n], h, lo);
        char* base = wsb + WB + l * LSTR + 8192 + (kf * 2 + t2) * 2048 + 2 * r3;
        *(short*)(base) = h;
        *(short*)(base + 1024) = lo;
        return;
    }
    t -= 40960;
    if (t < 1024) {  // wimg frags (K padded 26->32)
        int tt = t >> 9, r = t & 511, lane = r >> 3, j = r & 7;
        int k = (lane >> 4) * 8 + j, n = 16 * tt + (lane & 15);
        float v = (k < 26) ? wimg[k * 32 + n] : 0.0f;
        short h, lo;
        split1(v, h, lo);
        ((short*)(wsb + OFF_WIH))[t] = h;
        ((short*)(wsb + OFF_WIL))[t] = lo;
        return;
    }
    t -= 1024;
    if (t < 1024) {  // wscale frags (K padded 24->32)
        int tt = t >> 9, r = t & 511, lane = r >> 3, j = r & 7;
        int k = (lane >> 4) * 8 + j, n = 16 * tt + (lane & 15);
        float v = (k < 24) ? wsc[k * 32 + n] : 0.0f;
        short h, lo;
        split1(v, h, lo);
        ((short*)(wsb + OFF_WSH))[t] = h;
        ((short*)(wsb + OFF_WSL))[t] = lo;
        return;
    }
    t -= 1024;
    if (t < 5120) {  // bias1 quads: [l][t(4)][c(16)] x4 floats, bcast b1[l][16t+c]
        int l = t >> 8, r = t & 255;
        int tt = r >> 6, cc = (r >> 2) & 15;
        *(float*)(wsb + WB + l * LSTR + 16384 + 4 * r) = b1[l * 64 + tt * 16 + cc];
        return;
    }
    t -= 5120;
    if (t < 2560) {  // bias2 quads: [l][t2(2)][c(16)] x4 floats, bcast b2[l][16t2+c]
        int l = t >> 7, r = t & 127;
        int t2 = r >> 6, cc = (r >> 2) & 15;
        *(float*)(wsb + WB + l * LSTR + 17408 + 4 * r) = b2[l * 32 + t2 * 16 + cc];
        return;
    }
}

// load A-frag of X[16,32] for rows base..base+15 (cols: 24 md, iobs, sig, pad)
__device__ __forceinline__ void load_xfrag(
    const float* __restrict__ md, const float* __restrict__ iobs,
    const float* __restrict__ sig, int base, int q, int c,
    bf16x8& ah, bf16x8& al) {
    float xa[8];
    if (q < 3) {
        const f32x4* rp = (const f32x4*)(md + (size_t)(base + c) * DMETA + q * 8);
        f32x4 v0 = rp[0], v1 = rp[1];
#pragma unroll
        for (int j = 0; j < 4; ++j) { xa[j] = v0[j]; xa[4 + j] = v1[j]; }
    } else {
        xa[0] = iobs ? iobs[base + c] : 0.0f;
        xa[1] = sig ? sig[base + c] : 0.0f;
#pragma unroll
        for (int j = 2; j < 8; ++j) xa[j] = 0.0f;
    }
    split8p(xa, ah, al);
}

// pass A: input proj -> mlp20 (2 tiles/wave) -> segment-sum (uniform-id fast path)
__global__ __launch_bounds__(128, 4) void pass_a(
    const float* __restrict__ md, const float* __restrict__ iobs,
    const float* __restrict__ sig, const float* __restrict__ bimg,
    const char* __restrict__ wsb, const int* __restrict__ ids,
    float* __restrict__ sums) {
    __shared__ __attribute__((aligned(16))) float smat[2][TILE_F];
    int lane = threadIdx.x & 63, w = threadIdx.x >> 6;
    int q = lane >> 4, c = lane & 15;
    int i0 = (blockIdx.x * 2 + w) * 32;
    float* smw = &smat[w][0];

    bf16x8 ah0, al0, ah1, al1;
    load_xfrag(md, iobs, sig, i0, q, c, ah0, al0);
    load_xfrag(md, iobs, sig, i0 + 16, q, c, ah1, al1);

    float hC0[8], hC1[8];
    input_proj(ah0, al0, (const short*)(wsb + OFF_WIH), (const short*)(wsb + OFF_WIL),
               bimg, hC0, lane, c);
    input_proj(ah1, al1, (const short*)(wsb + OFF_WIH), (const short*)(wsb + OFF_WIL),
               bimg, hC1, lane, c);

    mlp20_x2(hC0, hC1, smw, wsb, lane, q, c);

#pragma unroll
    for (int tile = 0; tile < 2; ++tile) {
        const float* hC = tile ? hC1 : hC0;
        int tb = i0 + tile * 16;
        bool uni = (ids[tb] == ids[tb + 15]);   // wave-uniform branch
        if (uni) {
            int id = ids[tb];
#pragma unroll
            for (int t = 0; t < 2; ++t) {
                float s = (hC[t * 4 + 0] + hC[t * 4 + 1]) + (hC[t * 4 + 2] + hC[t * 4 + 3]);
                s += __shfl_xor(s, 16, 64);
                s += __shfl_xor(s, 32, 64);
                if (q == 0) atomicAdd(&sums[id * 32 + 16 * t + c], s);
            }
        } else {
            int idv[4];
#pragma unroll
            for (int r = 0; r < 4; ++r) idv[r] = ids[tb + q * 4 + r];
#pragma unroll
            for (int t = 0; t < 2; ++t)
#pragma unroll
                for (int r = 0; r < 4; ++r)
                    atomicAdd(&sums[idv[r] * 32 + 16 * t + c], hC[t * 4 + r]);
        }
    }
}

__global__ __launch_bounds__(256) void normalize_kernel(float* __restrict__ sums,
                                                        const int* __restrict__ cnts) {
    int t = blockIdx.x * 256 + threadIdx.x;
    if (t < NIMG * WIDTH) {
        int img = t >> 5;
        float cc = (float)max(cnts[img], 1);
        sums[t] = sums[t] / cc;
    }
}

// pass B: input proj + pooled -> mlp20 (2 tiles/wave) -> head -> sample -> z, kl
__global__ __launch_bounds__(128, 4) void pass_b(
    const float* __restrict__ md, const float* __restrict__ bsc,
    const char* __restrict__ wsb, const float* __restrict__ wout,
    const float* __restrict__ bout, const int* __restrict__ ids,
    const float* __restrict__ pooled, float* __restrict__ out) {
    __shared__ __attribute__((aligned(16))) float smat[2][TILE_F];
    __shared__ float sls[2][64];
    int lane = threadIdx.x & 63, w = threadIdx.x >> 6;
    int q = lane >> 4, c = lane & 15;
    int i0 = (blockIdx.x * 2 + w) * 32;
    float* smw = &smat[w][0];

    bf16x8 ah0, al0, ah1, al1;
    load_xfrag(md, nullptr, nullptr, i0, q, c, ah0, al0);
    load_xfrag(md, nullptr, nullptr, i0 + 16, q, c, ah1, al1);

    float hC0[8], hC1[8];
    input_proj(ah0, al0, (const short*)(wsb + OFF_WSH), (const short*)(wsb + OFF_WSL),
               bsc, hC0, lane, c);
    input_proj(ah1, al1, (const short*)(wsb + OFF_WSH), (const short*)(wsb + OFF_WSL),
               bsc, hC1, lane, c);
    // add pooled[id] per row
#pragma unroll
    for (int tile = 0; tile < 2; ++tile) {
        float* hC = tile ? hC1 : hC0;
        int tb = i0 + tile * 16;
        int idv[4];
#pragma unroll
        for (int r = 0; r < 4; ++r) idv[r] = ids[tb + q * 4 + r];
#pragma unroll
        for (int t = 0; t < 2; ++t)
#pragma unroll
            for (int r = 0; r < 4; ++r)
                hC[t * 4 + r] += pooled[idv[r] * 32 + 16 * t + c];
    }

    mlp20_x2(hC0, hC1, smw, wsb, lane, q, c);

    // head per tile: params = h @ wout + bout (reduce across the 16 c-lanes)
    float wo0[2], wo1[2];
#pragma unroll
    for (int t = 0; t < 2; ++t) {
        float2 wv = ((const float2*)wout)[16 * t + c];
        wo0[t] = wv.x; wo1[t] = wv.y;
    }
#pragma unroll
    for (int tile = 0; tile < 2; ++tile) {
        const float* hC = tile ? hC1 : hC0;
        float p0r[4], p1r[4];
#pragma unroll
        for (int r = 0; r < 4; ++r) {
            p0r[r] = hC[r] * wo0[0] + hC[4 + r] * wo0[1];
            p1r[r] = hC[r] * wo1[0] + hC[4 + r] * wo1[1];
        }
#pragma unroll
        for (int m = 1; m < 16; m <<= 1) {
#pragma unroll
            for (int r = 0; r < 4; ++r) {
                p0r[r] += __shfl_xor(p0r[r], m, 64);
                p1r[r] += __shfl_xor(p1r[r], m, 64);
            }
        }
        if (c == 0) {
#pragma unroll
            for (int r = 0; r < 4; ++r) {
                float loc = p0r[r] + bout[0];
                float pb = p1r[r] + bout[1];
                float scale = fmaxf(pb, 0.0f) + log1pf(expf(-fabsf(pb))) + 1e-12f;
                sls[w][tile * 16 + q * 4 + r] = loc;
                sls[w][32 + tile * 16 + q * 4 + r] = scale;
            }
        }
    }

    // sampling: lane covers row (i0 + lane&31), draws half*16..+15
    int ro = lane & 31, half = lane >> 5;
    int row = i0 + ro;
    float L = sls[w][ro];
    float S = sls[w][32 + ro];
    float lsg = logf(S);
    float kp = 0.0f;
    float* zrow = out + (size_t)row * MC + half * 16;
#pragma unroll 4
    for (int s4 = 0; s4 < 4; ++s4) {
        f32x4 zv;
#pragma unroll
        for (int jj = 0; jj < 4; ++jj) {
            int t = half * 16 + s4 * 4 + jj;
            uint32_t j = (uint32_t)(t * N_ROWS) + (uint32_t)row;
            float n = bits_to_normal(tf_bits(j));
            float z = fmaf(S, n, L);
            zv[jj] = z;
            kp += fmaf(-0.5f, n * n, fabsf(z));
        }
        *(f32x4*)(zrow + s4 * 4) = zv;
    }
    kp += __shfl_xor(kp, 32, 64);
    if (half == 0) {
        out[(size_t)N_ROWS * MC + row] =
            0.01f * (kp * (1.0f / 32.0f) - lsg - 0.91893853320467274f + 0.69314718055994531f);
    }
}

extern "C" void kernel_launch(void* const* d_in, const int* in_sizes, int n_in,
                              void* d_out, int out_size, void* d_ws, size_t ws_size,
                              hipStream_t stream) {
    const float* md   = (const float*)d_in[0];
    const float* iobs = (const float*)d_in[1];
    const float* sig  = (const float*)d_in[2];
    const float* wimg = (const float*)d_in[3];
    const float* bimg = (const float*)d_in[4];
    const float* wsc  = (const float*)d_in[5];
    const float* bsc  = (const float*)d_in[6];
    const float* w1   = (const float*)d_in[7];
    const float* b1   = (const float*)d_in[8];
    const float* w2   = (const float*)d_in[9];
    const float* b2   = (const float*)d_in[10];
    const float* wout = (const float*)d_in[11];
    const float* bout = (const float*)d_in[12];
    const int* ids    = (const int*)d_in[13];
    const int* cnts   = (const int*)d_in[14];
    float* out = (float*)d_out;
    char* wsb = (char*)d_ws;
    float* sums = (float*)wsb;

    const int nblk = N_ROWS / 64;  // 3125 blocks x 2 waves x 32 rows, exact
    prep_kernel<<<421, 256, 0, stream>>>(w1, w2, wimg, wsc, b1, b2, wsb);
    pass_a<<<nblk, 128, 0, stream>>>(md, iobs, sig, bimg, wsb, ids, sums);
    normalize_kernel<<<(NIMG * WIDTH + 255) / 256, 256, 0, stream>>>(sums, cnts);
    pass_b<<<nblk, 128, 0, stream>>>(md, bsc, wsb, wout, bout, ids, sums, out);
}